// Round 3
// baseline (6613.575 us; speedup 1.0000x reference)
//
#include <hip/hip_runtime.h>
#include <hip/hip_bf16.h>
#include <stdint.h>

typedef unsigned short u16;
typedef unsigned int   u32;

__device__ __forceinline__ float us2f(u16 u){ return __uint_as_float(((u32)u)<<16); }
__device__ __forceinline__ float lo2f(u32 w){ return __uint_as_float(w<<16); }
__device__ __forceinline__ float hi2f(u32 w){ return __uint_as_float(w & 0xffff0000u); }
__device__ __forceinline__ u16 f2us(float f){
  u32 u = __float_as_uint(f);
  u32 r = (u + 0x7FFFu + ((u>>16)&1u)) >> 16;   // RNE
  return (u16)r;
}

// ---------------- spatial layer ----------------
// in: (32,CI,64,64) f32 ; W: (64,31,CI,64,3) f32 ; bias: (64,31) f32 ; out: (32,31,64,64) f32
// out[b,o,h,w] = relu(bias[h,o] + sum_{i,r,dw} in[b,i,r,w+dw-1]*W[h,o,i,r,dw])
__global__ __launch_bounds__(128) void k_spatial(const float* __restrict__ in,
        const float* __restrict__ W, const float* __restrict__ bias,
        float* __restrict__ out, int CI){
  __shared__ float inA[2][64][66];   // [b-local][r][w+1], cols 0 and 65 are zero borders
  __shared__ float Wl[64][3][32];    // [r][dw][o]  (o padded to 32, col 31 zeroed)
  const int t  = threadIdx.x;
  const int wq = t & 31;
  const int bq = (t>>5)&1;
  const int og = t>>6;               // wave-uniform o-group (16 o's)
  const int h  = blockIdx.y;
  const int b0 = blockIdx.x*2;

  { int r = t & 63, bb = t>>6; inA[bb][r][0] = 0.f; inA[bb][r][65] = 0.f; }

  float accL[16], accH[16];
  #pragma unroll
  for (int j=0;j<16;j++){
    int o = og*16+j;
    float bv = (o<31)? bias[h*31+o] : 0.f;
    accL[j]=bv; accH[j]=bv;
  }

  for (int i=0;i<CI;i++){
    __syncthreads();
    // stage input tile: 2 batches x 64 rows x 64 px, float4
    for (int idx=t; idx<2048; idx+=128){
      int b2 = idx>>10, rem = idx&1023, r = rem>>4, w4 = (rem&15)*4;
      float4 v = *(const float4*)&in[ (((size_t)(b0+b2)*CI + i)*64 + r)*64 + w4 ];
      float* dst = &inA[b2][r][w4+1];
      dst[0]=v.x; dst[1]=v.y; dst[2]=v.z; dst[3]=v.w;
    }
    // stage weights [r][dw][o], zero o=31
    for (int idx=t; idx<6144; idx+=128){
      int r = idx/96, rem = idx-96*r, dw = rem>>5, o2 = rem&31;
      float v = 0.f;
      if (o2<31) v = W[ ((size_t)(h*31+o2)*CI + i)*192 + r*3 + dw ];
      Wl[r][dw][o2] = v;
    }
    __syncthreads();
    #pragma unroll 2
    for (int r=0;r<64;r++){
      float a0 = inA[bq][r][wq+0],  a1 = inA[bq][r][wq+1],  a2 = inA[bq][r][wq+2];
      float c0 = inA[bq][r][wq+32], c1 = inA[bq][r][wq+33], c2v= inA[bq][r][wq+34];
      const float4* w0p = (const float4*)&Wl[r][0][og*16];
      const float4* w1p = (const float4*)&Wl[r][1][og*16];
      const float4* w2p = (const float4*)&Wl[r][2][og*16];
      #pragma unroll
      for (int q=0;q<4;q++){
        float4 w0 = w0p[q], w1 = w1p[q], w2 = w2p[q];
        accL[q*4+0] = fmaf(a0,w0.x, fmaf(a1,w1.x, fmaf(a2,w2.x, accL[q*4+0])));
        accL[q*4+1] = fmaf(a0,w0.y, fmaf(a1,w1.y, fmaf(a2,w2.y, accL[q*4+1])));
        accL[q*4+2] = fmaf(a0,w0.z, fmaf(a1,w1.z, fmaf(a2,w2.z, accL[q*4+2])));
        accL[q*4+3] = fmaf(a0,w0.w, fmaf(a1,w1.w, fmaf(a2,w2.w, accL[q*4+3])));
        accH[q*4+0] = fmaf(c0,w0.x, fmaf(c1,w1.x, fmaf(c2v,w2.x, accH[q*4+0])));
        accH[q*4+1] = fmaf(c0,w0.y, fmaf(c1,w1.y, fmaf(c2v,w2.y, accH[q*4+1])));
        accH[q*4+2] = fmaf(c0,w0.z, fmaf(c1,w1.z, fmaf(c2v,w2.z, accH[q*4+2])));
        accH[q*4+3] = fmaf(c0,w0.w, fmaf(c1,w1.w, fmaf(c2v,w2.w, accH[q*4+3])));
      }
    }
  }
  #pragma unroll
  for (int j=0;j<16;j++){
    int o = og*16+j;
    if (o<31){
      size_t base = (((size_t)(b0+bq)*31 + o)*64 + h)*64;
      out[base + wq]      = fmaxf(accL[j],0.f);
      out[base + wq + 32] = fmaxf(accH[j],0.f);
    }
  }
}

// ---------------- spectral: 9x9 conv (relu) fused with 1x1 conv (relu) ----------------
// block = (y-pair, b, group-local). hb out: bf16 [gl][b][c2(32)][y][x]
__global__ __launch_bounds__(256) void k_spec_ab(
    const float* __restrict__ s3,
    const float* __restrict__ We1a, const float* __restrict__ be1a,
    const float* __restrict__ We1b, const float* __restrict__ be1b,
    const float* __restrict__ We2a, const float* __restrict__ be2a,
    const float* __restrict__ We2b, const float* __restrict__ be2b,
    u16* __restrict__ hb, int g0){
  __shared__ __align__(16) unsigned char smemA[43200];
  float* inT  = (float*)smemA;                 // [3][10][72]  (i, y0-4..y0+5, x+4)
  u16*   waL  = (u16*)(smemA + 8640);          // [64][27][10] bf16 (dx padded to 10)
  float* redL = (float*)smemA;                 // phase-B overlay [128][64]
  __shared__ __align__(16) u16 haL[64*2*64];   // [c][yq][x] bf16
  __shared__ __align__(16) u16 wbL[64*32];     // [c][c2]    bf16

  const int t  = threadIdx.x;
  const int y0 = blockIdx.x*2;
  const int b  = blockIdx.y;
  const int gl = blockIdx.z;
  const int g  = g0 + gl;

  int C, cb; const float *wa, *ba, *wb, *bb;
  if (g==0)      { C=2; cb=0;  wa=We1a;              ba=be1a;    wb=We1b;        bb=be1b;    }
  else if (g==30){ C=2; cb=29; wa=We1a+64*2*81;      ba=be1a+64; wb=We1b+32*64;  bb=be1b+32; }
  else { int m=g-1; C=3; cb=m; wa=We2a+(size_t)m*64*3*81; ba=be2a+m*64; wb=We2b+m*32*64; bb=be2b+m*32; }

  // stage input tile (zero-padded), wa (dx padded to 10, bf16), wb (transposed to [c][c2], bf16)
  for (int idx=t; idx<2160; idx+=256){
    int i = idx/720, rem = idx-720*i, row = rem/72, col = rem-72*row;
    int yg = y0 - 4 + row, xg = col - 4;
    float v = 0.f;
    if (i < C && yg>=0 && yg<64 && xg>=0 && xg<64)
      v = s3[ (((size_t)b*31 + cb + i)*64 + yg)*64 + xg ];
    inT[idx] = v;
  }
  for (int idx=t; idx<17280; idx+=256){
    int c = idx/270, pos = idx-270*c, sub = pos/10, dx = pos-10*sub;
    u16 v = 0;
    if (sub < C*9 && dx < 9) v = f2us( wa[ (size_t)c*(C*81) + sub*9 + dx ] );
    waL[idx] = v;
  }
  for (int idx=t; idx<2048; idx+=256){
    int c = idx>>5, c2 = idx&31;
    wbL[idx] = f2us( wb[ c2*64 + c ] );
  }
  __syncthreads();

  // ---- phase A: 9x9 conv, each thread: one channel c, one y row, 32 x px ----
  {
    const int c  = t & 63;
    const int yq = (t>>6)&1;
    const int xt = t>>7;
    const int x0 = xt*32;
    float acc[32];
    #pragma unroll
    for (int p=0;p<32;p++) acc[p]=0.f;
    for (int i=0;i<C;i++){
      for (int dy=0; dy<9; dy++){
        const float4* rp4 = (const float4*)&inT[(i*10 + (yq+dy))*72 + x0];
        float f[40];
        #pragma unroll
        for (int q=0;q<10;q++){ float4 v = rp4[q]; f[q*4+0]=v.x; f[q*4+1]=v.y; f[q*4+2]=v.z; f[q*4+3]=v.w; }
        const u16* wrow = &waL[(c*27 + (i*9+dy))*10];
        float wv[9];
        #pragma unroll
        for (int dx=0;dx<9;dx++) wv[dx] = us2f(wrow[dx]);
        #pragma unroll
        for (int p=0;p<32;p++){
          #pragma unroll
          for (int dx=0;dx<9;dx++) acc[p] = fmaf(f[p+dx], wv[dx], acc[p]);
        }
      }
    }
    float bav = ba[c];
    #pragma unroll
    for (int p=0;p<32;p++){
      float v = fmaxf(acc[p]+bav, 0.f);
      haL[(c*2 + yq)*64 + x0 + p] = f2us(v);
    }
  }
  __syncthreads();

  // ---- phase B: 1x1 conv 64->32 with 4-way c split + LDS reduction ----
  const int s   = t & 63;
  const int cq  = t>>6;
  const int xg  = s & 15;
  const int yq2 = (s>>4)&1;
  const int c2g = s>>5;
  float acc[64];  // [jj (16 c2)][px (4)]
  #pragma unroll
  for (int j=0;j<64;j++) acc[j]=0.f;
  for (int c = cq*16; c < cq*16+16; c++){
    uint2 hv = *(const uint2*)&haL[(c*2 + yq2)*64 + xg*4];
    float a0=lo2f(hv.x), a1=hi2f(hv.x), a2=lo2f(hv.y), a3=hi2f(hv.y);
    const uint4* wp = (const uint4*)&wbL[c*32 + c2g*16];
    uint4 wA = wp[0], wB = wp[1];
    float wf[16];
    wf[0]=lo2f(wA.x); wf[1]=hi2f(wA.x); wf[2]=lo2f(wA.y); wf[3]=hi2f(wA.y);
    wf[4]=lo2f(wA.z); wf[5]=hi2f(wA.z); wf[6]=lo2f(wA.w); wf[7]=hi2f(wA.w);
    wf[8]=lo2f(wB.x); wf[9]=hi2f(wB.x); wf[10]=lo2f(wB.y); wf[11]=hi2f(wB.y);
    wf[12]=lo2f(wB.z); wf[13]=hi2f(wB.z); wf[14]=lo2f(wB.w); wf[15]=hi2f(wB.w);
    #pragma unroll
    for (int jj=0;jj<16;jj++){
      acc[jj*4+0] = fmaf(a0,wf[jj],acc[jj*4+0]);
      acc[jj*4+1] = fmaf(a1,wf[jj],acc[jj*4+1]);
      acc[jj*4+2] = fmaf(a2,wf[jj],acc[jj*4+2]);
      acc[jj*4+3] = fmaf(a3,wf[jj],acc[jj*4+3]);
    }
  }
  __syncthreads();
  if (cq >= 2){
    #pragma unroll
    for (int j=0;j<64;j++) redL[((cq-2)*64 + s)*64 + j] = acc[j];
  }
  __syncthreads();
  if (cq < 2){
    #pragma unroll
    for (int j=0;j<64;j++) acc[j] += redL[(cq*64 + s)*64 + j];
  }
  __syncthreads();
  if (cq == 1){
    #pragma unroll
    for (int j=0;j<64;j++) redL[s*64 + j] = acc[j];
  }
  __syncthreads();
  if (cq == 0){
    #pragma unroll
    for (int jj=0;jj<16;jj++){
      int c2 = c2g*16 + jj;
      float bbv = bb[c2];
      size_t base = (((size_t)gl*32 + b)*32 + c2)*4096 + (size_t)(y0+yq2)*64 + xg*4;
      #pragma unroll
      for (int px=0;px<4;px++){
        float v = fmaxf(acc[jj*4+px] + redL[s*64 + jj*4+px] + bbv, 0.f);
        hb[base + px] = f2us(v);
      }
    }
  }
}

// ---------------- spectral: 5x5 conv 32->1, writes rec f32 [g][b][y][x] ----------------
__global__ __launch_bounds__(256) void k_spec_c(
    const u16* __restrict__ hb, const float* __restrict__ We1c, const float* __restrict__ be1c,
    const float* __restrict__ We2c, const float* __restrict__ be2c,
    float* __restrict__ rec, int g0){
  __shared__ __align__(16) unsigned char smemC[52224 + 3200];
  u16*   hbT  = (u16*)smemC;                 // [32][12][68] bf16
  float* wcL  = (float*)(smemC + 52224);     // [32][25]
  float* redc = (float*)smemC;               // overlay after compute
  const int t  = threadIdx.x;
  const int y0 = blockIdx.x*8;
  const int b  = blockIdx.y;
  const int gl = blockIdx.z;
  const int g  = g0 + gl;
  const float *wc, *bc;
  if (g==0)      { wc = We1c;             bc = be1c;       }
  else if (g==30){ wc = We1c + 800;       bc = be1c + 1;   }
  else           { wc = We2c + (g-1)*800; bc = be2c + (g-1); }

  for (int idx=t; idx<26112; idx+=256){
    int c2 = idx/816, rem = idx-816*c2, row = rem/68, col = rem-68*row;
    int yg = y0-2+row, xg = col-2;
    u16 v = 0;
    if (yg>=0 && yg<64 && xg>=0 && xg<64)
      v = hb[ (((size_t)gl*32 + b)*32 + c2)*4096 + (size_t)yg*64 + xg ];
    hbT[idx] = v;
  }
  for (int idx=t; idx<800; idx+=256) wcL[idx] = wc[idx];
  __syncthreads();

  const int xt = t&7, yq = (t>>3)&7, cqt = t>>6;
  const int x0 = xt*8;
  float acc[8];
  #pragma unroll
  for (int p=0;p<8;p++) acc[p]=0.f;
  for (int c2 = cqt*8; c2 < cqt*8+8; c2++){
    #pragma unroll
    for (int dy=0;dy<5;dy++){
      const uint2* hp = (const uint2*)&hbT[(c2*12 + yq+dy)*68 + x0];
      uint2 v0 = hp[0], v1 = hp[1], v2 = hp[2];
      float h[12];
      h[0]=lo2f(v0.x); h[1]=hi2f(v0.x); h[2]=lo2f(v0.y); h[3]=hi2f(v0.y);
      h[4]=lo2f(v1.x); h[5]=hi2f(v1.x); h[6]=lo2f(v1.y); h[7]=hi2f(v1.y);
      h[8]=lo2f(v2.x); h[9]=hi2f(v2.x); h[10]=lo2f(v2.y); h[11]=hi2f(v2.y);
      #pragma unroll
      for (int dx=0;dx<5;dx++){
        float wv = wcL[c2*25 + dy*5 + dx];
        #pragma unroll
        for (int p=0;p<8;p++) acc[p] = fmaf(h[p+dx], wv, acc[p]);
      }
    }
  }
  __syncthreads();
  int slot = yq*8 + xt;
  if (cqt >= 2){
    #pragma unroll
    for (int p=0;p<8;p++) redc[((cqt-2)*64 + slot)*8 + p] = acc[p];
  }
  __syncthreads();
  if (cqt < 2){
    #pragma unroll
    for (int p=0;p<8;p++) acc[p] += redc[(cqt*64 + slot)*8 + p];
  }
  __syncthreads();
  if (cqt == 1){
    #pragma unroll
    for (int p=0;p<8;p++) redc[slot*8 + p] = acc[p];
  }
  __syncthreads();
  if (cqt == 0){
    float bcv = bc[0];
    size_t base = (((size_t)g*32 + b)*64 + (y0+yq))*64 + x0;
    #pragma unroll
    for (int p=0;p<8;p++) rec[base+p] = acc[p] + redc[slot*8 + p] + bcv;
  }
}

// ---------------- final: out[b,y,x,o] = s3[b,o,y,x] + rec[o,b,y,x] (f32) ----------------
__global__ __launch_bounds__(256) void k_final(const float* __restrict__ s3,
        const float* __restrict__ rec, float* __restrict__ out){
  __shared__ float tile[31][65];
  const int t = threadIdx.x;
  const int y = blockIdx.x & 63;
  const int b = blockIdx.x >> 6;
  for (int idx=t; idx<1984; idx+=256){
    int o = idx>>6, x = idx&63;
    tile[o][x] = s3[ (((size_t)b*31+o)*64 + y)*64 + x ]
               + rec[ (((size_t)o*32+b)*64 + y)*64 + x ];
  }
  __syncthreads();
  size_t base = ((size_t)b*4096 + (size_t)y*64)*31;
  for (int idx=t; idx<1984; idx+=256){
    int x = idx/31, o = idx-31*x;
    out[base+idx] = tile[o][x];
  }
}

extern "C" void kernel_launch(void* const* d_in, const int* in_sizes, int n_in,
                              void* d_out, int out_size, void* d_ws, size_t ws_size,
                              hipStream_t stream){
  const float* x    = (const float*)d_in[0];
  const float* W1   = (const float*)d_in[1];
  const float* b1   = (const float*)d_in[2];
  const float* W2   = (const float*)d_in[3];
  const float* b2   = (const float*)d_in[4];
  const float* W3   = (const float*)d_in[5];
  const float* b3   = (const float*)d_in[6];
  const float* We1a = (const float*)d_in[7];
  const float* be1a = (const float*)d_in[8];
  const float* We1b = (const float*)d_in[9];
  const float* be1b = (const float*)d_in[10];
  const float* We1c = (const float*)d_in[11];
  const float* be1c = (const float*)d_in[12];
  const float* We2a = (const float*)d_in[13];
  const float* be2a = (const float*)d_in[14];
  const float* We2b = (const float*)d_in[15];
  const float* be2b = (const float*)d_in[16];
  const float* We2c = (const float*)d_in[17];
  const float* be2c = (const float*)d_in[18];
  float* out = (float*)d_out;

  // fp32 workspace, 16 MiB slots with overlays:
  //   [0,16)  s3            (live until k_final)
  //   [16,32) s1 -> rec     (s1 dead after layer-2)
  //   [32,48) s2 -> hb      (s2 dead after layer-3)
  char* ws = (char*)d_ws;
  const size_t MB = 1024*1024;
  float* s3  = (float*)(ws + 0*MB);
  float* s1  = (float*)(ws + 16*MB);
  float* rec = (float*)(ws + 16*MB);
  float* s2  = (float*)(ws + 32*MB);
  const size_t GRP = (size_t)32*32*4096*2;   // 8 MiB per spectral group (bf16)

  size_t hbOff = 32*MB;  int CH = 1;
  if (ws_size >= 56*MB){
    hbOff = 48*MB;
    size_t c = (ws_size - 48*MB)/GRP;
    CH = (c > 8) ? 8 : (int)c;
  } else if (ws_size >= 48*MB){
    CH = 2;
  }
  u16* hb = (u16*)(ws + hbOff);

  dim3 gs(16,64), bs(128);
  k_spatial<<<gs,bs,0,stream>>>(x,  W1, b1, s1, 1);
  k_spatial<<<gs,bs,0,stream>>>(s1, W2, b2, s2, 31);
  k_spatial<<<gs,bs,0,stream>>>(s2, W3, b3, s3, 31);
  for (int g0=0; g0<31; g0+=CH){
    int c = 31 - g0; if (c > CH) c = CH;
    k_spec_ab<<<dim3(32,32,c),dim3(256),0,stream>>>(s3, We1a,be1a,We1b,be1b,We2a,be2a,We2b,be2b, hb, g0);
    k_spec_c <<<dim3(8,32,c),dim3(256),0,stream>>>(hb, We1c,be1c,We2c,be2c, rec, g0);
  }
  k_final<<<dim3(2048),dim3(256),0,stream>>>(s3, rec, out);
}

// Round 4
// 4626.458 us; speedup vs baseline: 1.4295x; 1.4295x over previous
//
#include <hip/hip_runtime.h>
#include <hip/hip_bf16.h>
#include <stdint.h>

typedef unsigned short u16;
typedef unsigned int   u32;
typedef __attribute__((ext_vector_type(8))) short bf16x8;
typedef __attribute__((ext_vector_type(4))) float f32x4;

__device__ __forceinline__ float us2f(u16 u){ return __uint_as_float(((u32)u)<<16); }
__device__ __forceinline__ float lo2f(u32 w){ return __uint_as_float(w<<16); }
__device__ __forceinline__ float hi2f(u32 w){ return __uint_as_float(w & 0xffff0000u); }
__device__ __forceinline__ u16 f2us(float f){
  u32 u = __float_as_uint(f);
  u32 r = (u + 0x7FFFu + ((u>>16)&1u)) >> 16;   // RNE
  return (u16)r;
}

// ---------------- spatial layer via MFMA bf16 ----------------
// in: (32,CI,64,64) f32 ; W: (64,31,CI,64,3) f32 ; bias: (64,31) f32 ; out: (32,31,64,64) f32
// out[b,o,h,w] = relu(bias[h,o] + sum_{i,r,dw} in[b,i,r,w+dw-1]*W[h,o,i,r,dw])
// GEMM per h: D[(w)][o] = sum_dw A_dw[w][(i,r)] * B_dw[(i,r)][o]
// Block: 256 thr = 4 waves; wave wv handles h = hg*4+wv; M-tile = 64 w (one b); N = 32 (o pad).
__global__ __launch_bounds__(256) void k_spatial_mfma(const float* __restrict__ in,
        const float* __restrict__ W, const float* __restrict__ bias,
        float* __restrict__ out, int CI){
  __shared__ __align__(16) u16 inT[66*72];     // [wext 0..65][r 0..71 pad] bf16, row=144B
  __shared__ __align__(16) u16 Bl[12*32*72];   // [(dw*4+h)][o][r pad] bf16
  const int t    = threadIdx.x;
  const int wv   = t>>6;
  const int lane = t&63;
  const int l15  = lane&15;
  const int quad = lane>>4;
  const int b    = blockIdx.x;
  const int hg   = blockIdx.y;
  const int h    = hg*4 + wv;

  // static zero regions (never overwritten by staging)
  if (t < 64){ inT[0*72 + t] = 0; inT[65*72 + t] = 0; }          // w-borders (conv pad)
  for (int idx=t; idx<12*72; idx+=256){                           // o=31 pad rows
    int dwh = idx/72, r = idx - dwh*72;
    Bl[(dwh*32 + 31)*72 + r] = 0;
  }

  f32x4 acc[2][4];
  #pragma unroll
  for (int n=0;n<2;n++)
    #pragma unroll
    for (int ms=0;ms<4;ms++) acc[n][ms] = (f32x4){0.f,0.f,0.f,0.f};

  for (int i=0;i<CI;i++){
    __syncthreads();
    // ---- stage A: in[b,i,r,w] -> inT[w+1][r] (bf16, transposed) ----
    #pragma unroll
    for (int q=0;q<4;q++){
      int flat = q*256 + t;            // 1024 float4-free: 64 r x 16 w4
      int r = flat>>4, w4 = (flat&15)*4;
      float4 v = *(const float4*)&in[ (((size_t)b*CI + i)*64 + r)*64 + w4 ];
      inT[(w4+1)*72 + r] = f2us(v.x);
      inT[(w4+2)*72 + r] = f2us(v.y);
      inT[(w4+3)*72 + r] = f2us(v.z);
      inT[(w4+4)*72 + r] = f2us(v.w);
    }
    // ---- stage B: W[hG,o,i,r,dw] -> Bl[(dw*4+hh)][o][r] (bf16) ----
    for (int flat=t; flat<5952; flat+=256){   // 4h x 31o x 48 float4
      int hh  = flat/1488;
      int rem = flat - hh*1488;
      int o   = rem/48, f4i = rem - o*48;
      int hG  = hg*4 + hh;
      float4 v = *(const float4*)&W[ (((size_t)hG*31 + o)*CI + i)*192 + f4i*4 ];
      int k0 = f4i*4;
      { int k=k0+0, r=k/3, dw=k-3*r; Bl[((dw*4+hh)*32+o)*72 + r] = f2us(v.x); }
      { int k=k0+1, r=k/3, dw=k-3*r; Bl[((dw*4+hh)*32+o)*72 + r] = f2us(v.y); }
      { int k=k0+2, r=k/3, dw=k-3*r; Bl[((dw*4+hh)*32+o)*72 + r] = f2us(v.z); }
      { int k=k0+3, r=k/3, dw=k-3*r; Bl[((dw*4+hh)*32+o)*72 + r] = f2us(v.w); }
    }
    __syncthreads();
    // ---- MFMA: for this i-chunk, K = 64 r = 2 halves of 32 ----
    #pragma unroll
    for (int kh=0; kh<2; kh++){
      #pragma unroll
      for (int dw=0; dw<3; dw++){
        bf16x8 afr[4];
        #pragma unroll
        for (int ms=0;ms<4;ms++)
          afr[ms] = *(const bf16x8*)&inT[(ms*16 + l15 + dw)*72 + kh*32 + quad*8];
        #pragma unroll
        for (int n=0;n<2;n++){
          bf16x8 bfr = *(const bf16x8*)&Bl[((dw*4+wv)*32 + n*16 + l15)*72 + kh*32 + quad*8];
          #pragma unroll
          for (int ms=0;ms<4;ms++)
            acc[n][ms] = __builtin_amdgcn_mfma_f32_16x16x32_bf16(afr[ms], bfr, acc[n][ms], 0,0,0);
        }
      }
    }
  }
  // ---- epilogue: D col(n)=lane&15 -> o, row(m)=quad*4+reg -> w ----
  #pragma unroll
  for (int n=0;n<2;n++){
    int o = n*16 + l15;
    if (o < 31){
      float bv = bias[h*31 + o];
      #pragma unroll
      for (int ms=0;ms<4;ms++){
        size_t base = (((size_t)b*31 + o)*64 + h)*64 + ms*16 + quad*4;
        #pragma unroll
        for (int reg=0;reg<4;reg++)
          out[base + reg] = fmaxf(acc[n][ms][reg] + bv, 0.f);
      }
    }
  }
}

// ---------------- spectral: 9x9 conv (relu) fused with 1x1 conv (relu) ----------------
// block = (y-pair, b, group-local). hb out: bf16 [gl][b][c2(32)][y][x]
__global__ __launch_bounds__(256) void k_spec_ab(
    const float* __restrict__ s3,
    const float* __restrict__ We1a, const float* __restrict__ be1a,
    const float* __restrict__ We1b, const float* __restrict__ be1b,
    const float* __restrict__ We2a, const float* __restrict__ be2a,
    const float* __restrict__ We2b, const float* __restrict__ be2b,
    u16* __restrict__ hb, int g0){
  __shared__ __align__(16) unsigned char smemA[43200];
  float* inT  = (float*)smemA;                 // [3][10][72]  (i, y0-4..y0+5, x+4)
  u16*   waL  = (u16*)(smemA + 8640);          // [64][27][10] bf16 (dx padded to 10)
  float* redL = (float*)smemA;                 // phase-B overlay [128][64]
  __shared__ __align__(16) u16 haL[64*2*64];   // [c][yq][x] bf16
  __shared__ __align__(16) u16 wbL[64*32];     // [c][c2]    bf16

  const int t  = threadIdx.x;
  const int y0 = blockIdx.x*2;
  const int b  = blockIdx.y;
  const int gl = blockIdx.z;
  const int g  = g0 + gl;

  int C, cb; const float *wa, *ba, *wb, *bb;
  if (g==0)      { C=2; cb=0;  wa=We1a;              ba=be1a;    wb=We1b;        bb=be1b;    }
  else if (g==30){ C=2; cb=29; wa=We1a+64*2*81;      ba=be1a+64; wb=We1b+32*64;  bb=be1b+32; }
  else { int m=g-1; C=3; cb=m; wa=We2a+(size_t)m*64*3*81; ba=be2a+m*64; wb=We2b+m*32*64; bb=be2b+m*32; }

  for (int idx=t; idx<2160; idx+=256){
    int i = idx/720, rem = idx-720*i, row = rem/72, col = rem-72*row;
    int yg = y0 - 4 + row, xg = col - 4;
    float v = 0.f;
    if (i < C && yg>=0 && yg<64 && xg>=0 && xg<64)
      v = s3[ (((size_t)b*31 + cb + i)*64 + yg)*64 + xg ];
    inT[idx] = v;
  }
  for (int idx=t; idx<17280; idx+=256){
    int c = idx/270, pos = idx-270*c, sub = pos/10, dx = pos-10*sub;
    u16 v = 0;
    if (sub < C*9 && dx < 9) v = f2us( wa[ (size_t)c*(C*81) + sub*9 + dx ] );
    waL[idx] = v;
  }
  for (int idx=t; idx<2048; idx+=256){
    int c = idx>>5, c2 = idx&31;
    wbL[idx] = f2us( wb[ c2*64 + c ] );
  }
  __syncthreads();

  {
    const int c  = t & 63;
    const int yq = (t>>6)&1;
    const int xt = t>>7;
    const int x0 = xt*32;
    float acc[32];
    #pragma unroll
    for (int p=0;p<32;p++) acc[p]=0.f;
    for (int i=0;i<C;i++){
      for (int dy=0; dy<9; dy++){
        const float4* rp4 = (const float4*)&inT[(i*10 + (yq+dy))*72 + x0];
        float f[40];
        #pragma unroll
        for (int q=0;q<10;q++){ float4 v = rp4[q]; f[q*4+0]=v.x; f[q*4+1]=v.y; f[q*4+2]=v.z; f[q*4+3]=v.w; }
        const u16* wrow = &waL[(c*27 + (i*9+dy))*10];
        float wv[9];
        #pragma unroll
        for (int dx=0;dx<9;dx++) wv[dx] = us2f(wrow[dx]);
        #pragma unroll
        for (int p=0;p<32;p++){
          #pragma unroll
          for (int dx=0;dx<9;dx++) acc[p] = fmaf(f[p+dx], wv[dx], acc[p]);
        }
      }
    }
    float bav = ba[c];
    #pragma unroll
    for (int p=0;p<32;p++){
      float v = fmaxf(acc[p]+bav, 0.f);
      haL[(c*2 + yq)*64 + x0 + p] = f2us(v);
    }
  }
  __syncthreads();

  const int s   = t & 63;
  const int cq  = t>>6;
  const int xg  = s & 15;
  const int yq2 = (s>>4)&1;
  const int c2g = s>>5;
  float acc[64];
  #pragma unroll
  for (int j=0;j<64;j++) acc[j]=0.f;
  for (int c = cq*16; c < cq*16+16; c++){
    uint2 hv = *(const uint2*)&haL[(c*2 + yq2)*64 + xg*4];
    float a0=lo2f(hv.x), a1=hi2f(hv.x), a2=lo2f(hv.y), a3=hi2f(hv.y);
    const uint4* wp = (const uint4*)&wbL[c*32 + c2g*16];
    uint4 wA = wp[0], wB = wp[1];
    float wf[16];
    wf[0]=lo2f(wA.x); wf[1]=hi2f(wA.x); wf[2]=lo2f(wA.y); wf[3]=hi2f(wA.y);
    wf[4]=lo2f(wA.z); wf[5]=hi2f(wA.z); wf[6]=lo2f(wA.w); wf[7]=hi2f(wA.w);
    wf[8]=lo2f(wB.x); wf[9]=hi2f(wB.x); wf[10]=lo2f(wB.y); wf[11]=hi2f(wB.y);
    wf[12]=lo2f(wB.z); wf[13]=hi2f(wB.z); wf[14]=lo2f(wB.w); wf[15]=hi2f(wB.w);
    #pragma unroll
    for (int jj=0;jj<16;jj++){
      acc[jj*4+0] = fmaf(a0,wf[jj],acc[jj*4+0]);
      acc[jj*4+1] = fmaf(a1,wf[jj],acc[jj*4+1]);
      acc[jj*4+2] = fmaf(a2,wf[jj],acc[jj*4+2]);
      acc[jj*4+3] = fmaf(a3,wf[jj],acc[jj*4+3]);
    }
  }
  __syncthreads();
  if (cq >= 2){
    #pragma unroll
    for (int j=0;j<64;j++) redL[((cq-2)*64 + s)*64 + j] = acc[j];
  }
  __syncthreads();
  if (cq < 2){
    #pragma unroll
    for (int j=0;j<64;j++) acc[j] += redL[(cq*64 + s)*64 + j];
  }
  __syncthreads();
  if (cq == 1){
    #pragma unroll
    for (int j=0;j<64;j++) redL[s*64 + j] = acc[j];
  }
  __syncthreads();
  if (cq == 0){
    #pragma unroll
    for (int jj=0;jj<16;jj++){
      int c2 = c2g*16 + jj;
      float bbv = bb[c2];
      size_t base = (((size_t)gl*32 + b)*32 + c2)*4096 + (size_t)(y0+yq2)*64 + xg*4;
      #pragma unroll
      for (int px=0;px<4;px++){
        float v = fmaxf(acc[jj*4+px] + redL[s*64 + jj*4+px] + bbv, 0.f);
        hb[base + px] = f2us(v);
      }
    }
  }
}

// ---------------- spectral: 5x5 conv 32->1, writes rec f32 [g][b][y][x] ----------------
__global__ __launch_bounds__(256) void k_spec_c(
    const u16* __restrict__ hb, const float* __restrict__ We1c, const float* __restrict__ be1c,
    const float* __restrict__ We2c, const float* __restrict__ be2c,
    float* __restrict__ rec, int g0){
  __shared__ __align__(16) unsigned char smemC[52224 + 3200];
  u16*   hbT  = (u16*)smemC;                 // [32][12][68] bf16
  float* wcL  = (float*)(smemC + 52224);     // [32][25]
  float* redc = (float*)smemC;               // overlay after compute
  const int t  = threadIdx.x;
  const int y0 = blockIdx.x*8;
  const int b  = blockIdx.y;
  const int gl = blockIdx.z;
  const int g  = g0 + gl;
  const float *wc, *bc;
  if (g==0)      { wc = We1c;             bc = be1c;       }
  else if (g==30){ wc = We1c + 800;       bc = be1c + 1;   }
  else           { wc = We2c + (g-1)*800; bc = be2c + (g-1); }

  for (int idx=t; idx<26112; idx+=256){
    int c2 = idx/816, rem = idx-816*c2, row = rem/68, col = rem-68*row;
    int yg = y0-2+row, xg = col-2;
    u16 v = 0;
    if (yg>=0 && yg<64 && xg>=0 && xg<64)
      v = hb[ (((size_t)gl*32 + b)*32 + c2)*4096 + (size_t)yg*64 + xg ];
    hbT[idx] = v;
  }
  for (int idx=t; idx<800; idx+=256) wcL[idx] = wc[idx];
  __syncthreads();

  const int xt = t&7, yq = (t>>3)&7, cqt = t>>6;
  const int x0 = xt*8;
  float acc[8];
  #pragma unroll
  for (int p=0;p<8;p++) acc[p]=0.f;
  for (int c2 = cqt*8; c2 < cqt*8+8; c2++){
    #pragma unroll
    for (int dy=0;dy<5;dy++){
      const uint2* hp = (const uint2*)&hbT[(c2*12 + yq+dy)*68 + x0];
      uint2 v0 = hp[0], v1 = hp[1], v2 = hp[2];
      float h[12];
      h[0]=lo2f(v0.x); h[1]=hi2f(v0.x); h[2]=lo2f(v0.y); h[3]=hi2f(v0.y);
      h[4]=lo2f(v1.x); h[5]=hi2f(v1.x); h[6]=lo2f(v1.y); h[7]=hi2f(v1.y);
      h[8]=lo2f(v2.x); h[9]=hi2f(v2.x); h[10]=lo2f(v2.y); h[11]=hi2f(v2.y);
      #pragma unroll
      for (int dx=0;dx<5;dx++){
        float wv = wcL[c2*25 + dy*5 + dx];
        #pragma unroll
        for (int p=0;p<8;p++) acc[p] = fmaf(h[p+dx], wv, acc[p]);
      }
    }
  }
  __syncthreads();
  int slot = yq*8 + xt;
  if (cqt >= 2){
    #pragma unroll
    for (int p=0;p<8;p++) redc[((cqt-2)*64 + slot)*8 + p] = acc[p];
  }
  __syncthreads();
  if (cqt < 2){
    #pragma unroll
    for (int p=0;p<8;p++) acc[p] += redc[(cqt*64 + slot)*8 + p];
  }
  __syncthreads();
  if (cqt == 1){
    #pragma unroll
    for (int p=0;p<8;p++) redc[slot*8 + p] = acc[p];
  }
  __syncthreads();
  if (cqt == 0){
    float bcv = bc[0];
    size_t base = (((size_t)g*32 + b)*64 + (y0+yq))*64 + x0;
    #pragma unroll
    for (int p=0;p<8;p++) rec[base+p] = acc[p] + redc[slot*8 + p] + bcv;
  }
}

// ---------------- final: out[b,y,x,o] = s3[b,o,y,x] + rec[o,b,y,x] (f32) ----------------
__global__ __launch_bounds__(256) void k_final(const float* __restrict__ s3,
        const float* __restrict__ rec, float* __restrict__ out){
  __shared__ float tile[31][65];
  const int t = threadIdx.x;
  const int y = blockIdx.x & 63;
  const int b = blockIdx.x >> 6;
  for (int idx=t; idx<1984; idx+=256){
    int o = idx>>6, x = idx&63;
    tile[o][x] = s3[ (((size_t)b*31+o)*64 + y)*64 + x ]
               + rec[ (((size_t)o*32+b)*64 + y)*64 + x ];
  }
  __syncthreads();
  size_t base = ((size_t)b*4096 + (size_t)y*64)*31;
  for (int idx=t; idx<1984; idx+=256){
    int x = idx/31, o = idx-31*x;
    out[base+idx] = tile[o][x];
  }
}

extern "C" void kernel_launch(void* const* d_in, const int* in_sizes, int n_in,
                              void* d_out, int out_size, void* d_ws, size_t ws_size,
                              hipStream_t stream){
  const float* x    = (const float*)d_in[0];
  const float* W1   = (const float*)d_in[1];
  const float* b1   = (const float*)d_in[2];
  const float* W2   = (const float*)d_in[3];
  const float* b2   = (const float*)d_in[4];
  const float* W3   = (const float*)d_in[5];
  const float* b3   = (const float*)d_in[6];
  const float* We1a = (const float*)d_in[7];
  const float* be1a = (const float*)d_in[8];
  const float* We1b = (const float*)d_in[9];
  const float* be1b = (const float*)d_in[10];
  const float* We1c = (const float*)d_in[11];
  const float* be1c = (const float*)d_in[12];
  const float* We2a = (const float*)d_in[13];
  const float* be2a = (const float*)d_in[14];
  const float* We2b = (const float*)d_in[15];
  const float* be2b = (const float*)d_in[16];
  const float* We2c = (const float*)d_in[17];
  const float* be2c = (const float*)d_in[18];
  float* out = (float*)d_out;

  // fp32 workspace, 16 MiB slots with overlays:
  //   [0,16)  s3            (live until k_final)
  //   [16,32) s1 -> rec     (s1 dead after layer-2)
  //   [32,48) s2 -> hb      (s2 dead after layer-3)
  char* ws = (char*)d_ws;
  const size_t MB = 1024*1024;
  float* s3  = (float*)(ws + 0*MB);
  float* s1  = (float*)(ws + 16*MB);
  float* rec = (float*)(ws + 16*MB);
  float* s2  = (float*)(ws + 32*MB);
  const size_t GRP = (size_t)32*32*4096*2;   // 8 MiB per spectral group (bf16)

  size_t hbOff = 32*MB;  int CH = 1;
  if (ws_size >= 56*MB){
    hbOff = 48*MB;
    size_t c = (ws_size - 48*MB)/GRP;
    CH = (c > 8) ? 8 : (int)c;
  } else if (ws_size >= 48*MB){
    CH = 2;
  }
  u16* hb = (u16*)(ws + hbOff);

  dim3 gmm(32,16), bmm(256);
  k_spatial_mfma<<<gmm,bmm,0,stream>>>(x,  W1, b1, s1, 1);
  k_spatial_mfma<<<gmm,bmm,0,stream>>>(s1, W2, b2, s2, 31);
  k_spatial_mfma<<<gmm,bmm,0,stream>>>(s2, W3, b3, s3, 31);
  for (int g0=0; g0<31; g0+=CH){
    int c = 31 - g0; if (c > CH) c = CH;
    k_spec_ab<<<dim3(32,32,c),dim3(256),0,stream>>>(s3, We1a,be1a,We1b,be1b,We2a,be2a,We2b,be2b, hb, g0);
    k_spec_c <<<dim3(8,32,c),dim3(256),0,stream>>>(hb, We1c,be1c,We2c,be2c, rec, g0);
  }
  k_final<<<dim3(2048),dim3(256),0,stream>>>(s3, rec, out);
}

// Round 5
// 2792.586 us; speedup vs baseline: 2.3683x; 1.6567x over previous
//
#include <hip/hip_runtime.h>
#include <hip/hip_bf16.h>
#include <stdint.h>

typedef unsigned short u16;
typedef unsigned int   u32;
typedef __attribute__((ext_vector_type(8))) short bf16x8;
typedef __attribute__((ext_vector_type(4))) float f32x4;

__device__ __forceinline__ float us2f(u16 u){ return __uint_as_float(((u32)u)<<16); }
__device__ __forceinline__ float lo2f(u32 w){ return __uint_as_float(w<<16); }
__device__ __forceinline__ float hi2f(u32 w){ return __uint_as_float(w & 0xffff0000u); }
__device__ __forceinline__ u16 f2us(float f){
  u32 u = __float_as_uint(f);
  u32 r = (u + 0x7FFFu + ((u>>16)&1u)) >> 16;   // RNE
  return (u16)r;
}

// ---------------- spatial layer via MFMA bf16 (unchanged from R4) ----------------
__global__ __launch_bounds__(256) void k_spatial_mfma(const float* __restrict__ in,
        const float* __restrict__ W, const float* __restrict__ bias,
        float* __restrict__ out, int CI){
  __shared__ __align__(16) u16 inT[66*72];     // [wext][r pad]
  __shared__ __align__(16) u16 Bl[12*32*72];   // [(dw*4+h)][o][r pad]
  const int t    = threadIdx.x;
  const int wv   = t>>6;
  const int lane = t&63;
  const int l15  = lane&15;
  const int quad = lane>>4;
  const int b    = blockIdx.x;
  const int hg   = blockIdx.y;
  const int h    = hg*4 + wv;

  if (t < 64){ inT[0*72 + t] = 0; inT[65*72 + t] = 0; }
  for (int idx=t; idx<12*72; idx+=256){
    int dwh = idx/72, r = idx - dwh*72;
    Bl[(dwh*32 + 31)*72 + r] = 0;
  }

  f32x4 acc[2][4];
  #pragma unroll
  for (int n=0;n<2;n++)
    #pragma unroll
    for (int ms=0;ms<4;ms++) acc[n][ms] = (f32x4){0.f,0.f,0.f,0.f};

  for (int i=0;i<CI;i++){
    __syncthreads();
    #pragma unroll
    for (int q=0;q<4;q++){
      int flat = q*256 + t;
      int r = flat>>4, w4 = (flat&15)*4;
      float4 v = *(const float4*)&in[ (((size_t)b*CI + i)*64 + r)*64 + w4 ];
      inT[(w4+1)*72 + r] = f2us(v.x);
      inT[(w4+2)*72 + r] = f2us(v.y);
      inT[(w4+3)*72 + r] = f2us(v.z);
      inT[(w4+4)*72 + r] = f2us(v.w);
    }
    for (int flat=t; flat<5952; flat+=256){
      int hh  = flat/1488;
      int rem = flat - hh*1488;
      int o   = rem/48, f4i = rem - o*48;
      int hG  = hg*4 + hh;
      float4 v = *(const float4*)&W[ (((size_t)hG*31 + o)*CI + i)*192 + f4i*4 ];
      int k0 = f4i*4;
      { int k=k0+0, r=k/3, dw=k-3*r; Bl[((dw*4+hh)*32+o)*72 + r] = f2us(v.x); }
      { int k=k0+1, r=k/3, dw=k-3*r; Bl[((dw*4+hh)*32+o)*72 + r] = f2us(v.y); }
      { int k=k0+2, r=k/3, dw=k-3*r; Bl[((dw*4+hh)*32+o)*72 + r] = f2us(v.z); }
      { int k=k0+3, r=k/3, dw=k-3*r; Bl[((dw*4+hh)*32+o)*72 + r] = f2us(v.w); }
    }
    __syncthreads();
    #pragma unroll
    for (int kh=0; kh<2; kh++){
      #pragma unroll
      for (int dw=0; dw<3; dw++){
        bf16x8 afr[4];
        #pragma unroll
        for (int ms=0;ms<4;ms++)
          afr[ms] = *(const bf16x8*)&inT[(ms*16 + l15 + dw)*72 + kh*32 + quad*8];
        #pragma unroll
        for (int n=0;n<2;n++){
          bf16x8 bfr = *(const bf16x8*)&Bl[((dw*4+wv)*32 + n*16 + l15)*72 + kh*32 + quad*8];
          #pragma unroll
          for (int ms=0;ms<4;ms++)
            acc[n][ms] = __builtin_amdgcn_mfma_f32_16x16x32_bf16(afr[ms], bfr, acc[n][ms], 0,0,0);
        }
      }
    }
  }
  #pragma unroll
  for (int n=0;n<2;n++){
    int o = n*16 + l15;
    if (o < 31){
      float bv = bias[h*31 + o];
      #pragma unroll
      for (int ms=0;ms<4;ms++){
        size_t base = (((size_t)b*31 + o)*64 + h)*64 + ms*16 + quad*4;
        #pragma unroll
        for (int reg=0;reg<4;reg++)
          out[base + reg] = fmaxf(acc[n][ms][reg] + bv, 0.f);
      }
    }
  }
}

// ---------------- prep: weights -> GEMM-ready bf16 ----------------
// waP[g][dx][c][40]: k=i*9+dy (real C*9, zero-pad to 40). wbP[g][c2][72].
__global__ __launch_bounds__(256) void k_prep(
    const float* __restrict__ We1a, const float* __restrict__ We2a,
    const float* __restrict__ We1b, const float* __restrict__ We2b,
    u16* __restrict__ waP, u16* __restrict__ wbP){
  int t = blockIdx.x*256 + threadIdx.x;
  if (t < 17856){
    int g = t/576, rem = t - g*576, dx = rem>>6, c = rem&63;
    int C; const float* wa;
    if (g==0)      { C=2; wa = We1a; }
    else if (g==30){ C=2; wa = We1a + 64*2*81; }
    else           { C=3; wa = We2a + (size_t)(g-1)*64*3*81; }
    const float* wrow = wa + (size_t)c*C*81;
    u16* dst = waP + ((size_t)(g*9 + dx)*64 + c)*40;
    int Kr = C*9;
    for (int k=0;k<40;k++){
      u16 v = 0;
      if (k < Kr) v = f2us(wrow[k*9 + dx]);
      dst[k] = v;
    }
  } else if (t < 17856 + 992){
    int u = t - 17856; int g = u>>5, c2 = u&31;
    const float* wb;
    if (g==0)      wb = We1b;
    else if (g==30) wb = We1b + 32*64;
    else            wb = We2b + (size_t)(g-1)*32*64;
    u16* dst = wbP + ((size_t)g*32 + c2)*72;
    for (int k=0;k<64;k++) dst[k] = f2us(wb[c2*64 + k]);
    for (int k=64;k<72;k++) dst[k] = 0;
  }
}

// ---------------- spectral a+b via MFMA ----------------
// Block: (yo 16, b 32), 4 y-rows (256 px), one group g per launch.
// Phase A: ha[px][c=64] = relu(ba + sum_dx A_dx[px][k=(i,dy)] * Ba[dx][c][k]), K pad 40 (real C*9).
// Phase B: hb[px][c2=32] = relu(bb + ha[px][c] * wb[c2][c]).
// hb out (bf16): [b][c2][y][x]  (matches k_spec_c with gl=0)
__global__ __launch_bounds__(256) void k_spec_ab(
    const float* __restrict__ s3,
    const u16* __restrict__ waP, const u16* __restrict__ wbP,
    const float* __restrict__ be1a, const float* __restrict__ be1b,
    const float* __restrict__ be2a, const float* __restrict__ be2b,
    u16* __restrict__ hb, int g){
  __shared__ __align__(16) unsigned char smem[69120];
  u16* Ba   = (u16*)smem;            // [9][64][40]  phase A
  u16* colT = (u16*)(smem + 46080);  // [4][72][40]  phase A
  u16* haT  = (u16*)smem;            // [256][72]    phase B (over Ba)
  u16* hbL  = (u16*)(smem + 46080);  // [32][288]    phase B (over colT)

  const int t = threadIdx.x;
  const int yo = blockIdx.x, b = blockIdx.y;
  const int y0 = yo*4;
  const int wv = t>>6, lane = t&63, l15 = lane&15, quad = lane>>4;

  int C, cb; const float *ba, *bb;
  if (g==0)      { C=2; cb=0;  ba=be1a;           bb=be1b;        }
  else if (g==30){ C=2; cb=29; ba=be1a+64;        bb=be1b+32;     }
  else           { C=3; cb=g-1; ba=be2a+(size_t)(g-1)*64; bb=be2b+(size_t)(g-1)*32; }

  // zero colT (pads must be finite-zero: garbage*0 = NaN risk in MFMA)
  {
    uint4 z = {0,0,0,0};
    uint4* c4 = (uint4*)colT;
    #pragma unroll
    for (int j=0;j<6;j++){ int idx = j*256 + t; if (idx < 1440) c4[idx] = z; }
  }
  // copy Ba (prepped, pads already zero)
  {
    const uint4* src = (const uint4*)(waP + (size_t)g*9*64*40);
    uint4* dst = (uint4*)Ba;
    #pragma unroll
    for (int j=0;j<12;j++){ int idx = j*256 + t; if (idx < 2880) dst[idx] = src[idx]; }
  }
  __syncthreads();

  // build colT[yl][xe][k] = bf16(s3[b][cb+i][y0+yl+dy-4][xe-4]), k=i*9+dy
  for (int idx=t; idx<576; idx+=256){
    int i = idx/192, rem = idx-192*i, yext = rem>>4, x4 = rem&15;
    int yrow = y0 + yext - 4;
    if (i < C && yrow >= 0 && yrow < 64){
      float4 v = *(const float4*)&s3[ (((size_t)b*31 + cb + i)*64 + yrow)*64 + x4*4 ];
      u16 q0=f2us(v.x), q1=f2us(v.y), q2=f2us(v.z), q3=f2us(v.w);
      #pragma unroll
      for (int yl=0; yl<4; yl++){
        int dy = yext - yl;
        if (dy >= 0 && dy < 9){
          int k = i*9 + dy;
          int base = (yl*72 + x4*4 + 4)*40 + k;
          colT[base      ] = q0;
          colT[base + 40 ] = q1;
          colT[base + 80 ] = q2;
          colT[base + 120] = q3;
        }
      }
    }
  }
  __syncthreads();

  // ---- phase A MFMA: wave wv owns x-chunk [wv*16, wv*16+16), all 4 yl ----
  f32x4 acc[4][4];
  #pragma unroll
  for (int yl=0;yl<4;yl++)
    #pragma unroll
    for (int nf=0;nf<4;nf++) acc[yl][nf] = (f32x4){0.f,0.f,0.f,0.f};

  #pragma unroll
  for (int dx=0; dx<9; dx++){
    bf16x8 af[4];
    #pragma unroll
    for (int yl=0;yl<4;yl++)
      af[yl] = *(const bf16x8*)&colT[(yl*72 + wv*16 + l15 + dx)*40 + quad*8];
    #pragma unroll
    for (int nf=0;nf<4;nf++){
      bf16x8 bfr = *(const bf16x8*)&Ba[((dx*64) + nf*16 + l15)*40 + quad*8];
      #pragma unroll
      for (int yl=0;yl<4;yl++)
        acc[yl][nf] = __builtin_amdgcn_mfma_f32_16x16x32_bf16(af[yl], bfr, acc[yl][nf], 0,0,0);
    }
  }
  __syncthreads();   // all Ba/colT reads done before overlays

  // epilogue A -> haT[px][c]
  #pragma unroll
  for (int nf=0;nf<4;nf++){
    float bav = ba[nf*16 + l15];
    #pragma unroll
    for (int yl=0;yl<4;yl++){
      int px = yl*64 + wv*16 + quad*4;
      #pragma unroll
      for (int reg=0;reg<4;reg++)
        haT[(px+reg)*72 + nf*16 + l15] = f2us(fmaxf(acc[yl][nf][reg] + bav, 0.f));
    }
  }
  __syncthreads();

  // ---- phase B: 1x1 conv 64->32; wave wv owns m-frags wv*4..wv*4+3 ----
  const u16* wb_g = wbP + (size_t)g*32*72;
  f32x4 acc2[4][2];
  #pragma unroll
  for (int j=0;j<4;j++){ acc2[j][0] = (f32x4){0.f,0.f,0.f,0.f}; acc2[j][1] = (f32x4){0.f,0.f,0.f,0.f}; }
  #pragma unroll
  for (int kh=0; kh<2; kh++){
    bf16x8 a2[4];
    #pragma unroll
    for (int j=0;j<4;j++)
      a2[j] = *(const bf16x8*)&haT[((wv*4+j)*16 + l15)*72 + kh*32 + quad*8];
    #pragma unroll
    for (int nf=0;nf<2;nf++){
      bf16x8 b2 = *(const bf16x8*)&wb_g[(nf*16 + l15)*72 + kh*32 + quad*8];
      #pragma unroll
      for (int j=0;j<4;j++)
        acc2[j][nf] = __builtin_amdgcn_mfma_f32_16x16x32_bf16(a2[j], b2, acc2[j][nf], 0,0,0);
    }
  }
  // epilogue B -> hbL[c2][px]
  #pragma unroll
  for (int nf=0;nf<2;nf++){
    float bbv = bb[nf*16 + l15];
    #pragma unroll
    for (int j=0;j<4;j++){
      int px = (wv*4+j)*16 + quad*4;
      #pragma unroll
      for (int reg=0;reg<4;reg++)
        hbL[(nf*16+l15)*288 + px + reg] = f2us(fmaxf(acc2[j][nf][reg] + bbv, 0.f));
    }
  }
  __syncthreads();

  // coalesced global write: hb[(b*32 + c2)*4096 + (y0+yl)*64 + x]
  {
    int c2 = t>>3, xq = t&7;
    size_t base = ((size_t)b*32 + c2)*4096 + (size_t)yo*256 + xq*32;
    #pragma unroll
    for (int q=0;q<4;q++)
      *(uint4*)&hb[base + q*8] = *(const uint4*)&hbL[c2*288 + xq*32 + q*8];
  }
}

// ---------------- spectral: 5x5 conv 32->1, writes rec f32 [g][b][y][x] ----------------
__global__ __launch_bounds__(256) void k_spec_c(
    const u16* __restrict__ hb, const float* __restrict__ We1c, const float* __restrict__ be1c,
    const float* __restrict__ We2c, const float* __restrict__ be2c,
    float* __restrict__ rec, int g0){
  __shared__ __align__(16) unsigned char smemC[52224 + 3200];
  u16*   hbT  = (u16*)smemC;                 // [32][12][68] bf16
  float* wcL  = (float*)(smemC + 52224);     // [32][25]
  float* redc = (float*)smemC;               // overlay after compute
  const int t  = threadIdx.x;
  const int y0 = blockIdx.x*8;
  const int b  = blockIdx.y;
  const int gl = blockIdx.z;
  const int g  = g0 + gl;
  const float *wc, *bc;
  if (g==0)      { wc = We1c;             bc = be1c;       }
  else if (g==30){ wc = We1c + 800;       bc = be1c + 1;   }
  else           { wc = We2c + (g-1)*800; bc = be2c + (g-1); }

  for (int idx=t; idx<26112; idx+=256){
    int c2 = idx/816, rem = idx-816*c2, row = rem/68, col = rem-68*row;
    int yg = y0-2+row, xg = col-2;
    u16 v = 0;
    if (yg>=0 && yg<64 && xg>=0 && xg<64)
      v = hb[ (((size_t)gl*32 + b)*32 + c2)*4096 + (size_t)yg*64 + xg ];
    hbT[idx] = v;
  }
  for (int idx=t; idx<800; idx+=256) wcL[idx] = wc[idx];
  __syncthreads();

  const int xt = t&7, yq = (t>>3)&7, cqt = t>>6;
  const int x0 = xt*8;
  float acc[8];
  #pragma unroll
  for (int p=0;p<8;p++) acc[p]=0.f;
  for (int c2 = cqt*8; c2 < cqt*8+8; c2++){
    #pragma unroll
    for (int dy=0;dy<5;dy++){
      const uint2* hp = (const uint2*)&hbT[(c2*12 + yq+dy)*68 + x0];
      uint2 v0 = hp[0], v1 = hp[1], v2 = hp[2];
      float h[12];
      h[0]=lo2f(v0.x); h[1]=hi2f(v0.x); h[2]=lo2f(v0.y); h[3]=hi2f(v0.y);
      h[4]=lo2f(v1.x); h[5]=hi2f(v1.x); h[6]=lo2f(v1.y); h[7]=hi2f(v1.y);
      h[8]=lo2f(v2.x); h[9]=hi2f(v2.x); h[10]=lo2f(v2.y); h[11]=hi2f(v2.y);
      #pragma unroll
      for (int dx=0;dx<5;dx++){
        float wv = wcL[c2*25 + dy*5 + dx];
        #pragma unroll
        for (int p=0;p<8;p++) acc[p] = fmaf(h[p+dx], wv, acc[p]);
      }
    }
  }
  __syncthreads();
  int slot = yq*8 + xt;
  if (cqt >= 2){
    #pragma unroll
    for (int p=0;p<8;p++) redc[((cqt-2)*64 + slot)*8 + p] = acc[p];
  }
  __syncthreads();
  if (cqt < 2){
    #pragma unroll
    for (int p=0;p<8;p++) acc[p] += redc[(cqt*64 + slot)*8 + p];
  }
  __syncthreads();
  if (cqt == 1){
    #pragma unroll
    for (int p=0;p<8;p++) redc[slot*8 + p] = acc[p];
  }
  __syncthreads();
  if (cqt == 0){
    float bcv = bc[0];
    size_t base = (((size_t)g*32 + b)*64 + (y0+yq))*64 + x0;
    #pragma unroll
    for (int p=0;p<8;p++) rec[base+p] = acc[p] + redc[slot*8 + p] + bcv;
  }
}

// ---------------- final: out[b,y,x,o] = s3[b,o,y,x] + rec[o,b,y,x] (f32) ----------------
__global__ __launch_bounds__(256) void k_final(const float* __restrict__ s3,
        const float* __restrict__ rec, float* __restrict__ out){
  __shared__ float tile[31][65];
  const int t = threadIdx.x;
  const int y = blockIdx.x & 63;
  const int b = blockIdx.x >> 6;
  for (int idx=t; idx<1984; idx+=256){
    int o = idx>>6, x = idx&63;
    tile[o][x] = s3[ (((size_t)b*31+o)*64 + y)*64 + x ]
               + rec[ (((size_t)o*32+b)*64 + y)*64 + x ];
  }
  __syncthreads();
  size_t base = ((size_t)b*4096 + (size_t)y*64)*31;
  for (int idx=t; idx<1984; idx+=256){
    int x = idx/31, o = idx-31*x;
    out[base+idx] = tile[o][x];
  }
}

extern "C" void kernel_launch(void* const* d_in, const int* in_sizes, int n_in,
                              void* d_out, int out_size, void* d_ws, size_t ws_size,
                              hipStream_t stream){
  const float* x    = (const float*)d_in[0];
  const float* W1   = (const float*)d_in[1];
  const float* b1   = (const float*)d_in[2];
  const float* W2   = (const float*)d_in[3];
  const float* b2   = (const float*)d_in[4];
  const float* W3   = (const float*)d_in[5];
  const float* b3   = (const float*)d_in[6];
  const float* We1a = (const float*)d_in[7];
  const float* be1a = (const float*)d_in[8];
  const float* We1b = (const float*)d_in[9];
  const float* be1b = (const float*)d_in[10];
  const float* We1c = (const float*)d_in[11];
  const float* be1c = (const float*)d_in[12];
  const float* We2a = (const float*)d_in[13];
  const float* be2a = (const float*)d_in[14];
  const float* We2b = (const float*)d_in[15];
  const float* be2b = (const float*)d_in[16];
  const float* We2c = (const float*)d_in[17];
  const float* be2c = (const float*)d_in[18];
  float* out = (float*)d_out;

  // ws (f32, 16 MiB slots): [0,16) s3 ; [16,32) s1 -> rec ; [32,48) s2
  char* ws = (char*)d_ws;
  const size_t MB = 1024*1024;
  float* s3  = (float*)(ws + 0*MB);
  float* s1  = (float*)(ws + 16*MB);
  float* rec = (float*)(ws + 16*MB);
  float* s2  = (float*)(ws + 32*MB);

  // d_out doubles as scratch until k_final overwrites all of it:
  //   [0, 1.44M)      waP (bf16)
  //   [1.44M, 1.59M)  wbP (bf16)
  //   [2M, 10.4M)     hb  (bf16, one group)
  u16* waP = (u16*)((char*)d_out);
  u16* wbP = (u16*)((char*)d_out + 1440000);
  u16* hb  = (u16*)((char*)d_out + 2097152);

  dim3 gmm(32,16), bmm(256);
  k_spatial_mfma<<<gmm,bmm,0,stream>>>(x,  W1, b1, s1, 1);
  k_spatial_mfma<<<gmm,bmm,0,stream>>>(s1, W2, b2, s2, 31);
  k_spatial_mfma<<<gmm,bmm,0,stream>>>(s2, W3, b3, s3, 31);
  k_prep<<<dim3(74),dim3(256),0,stream>>>(We1a, We2a, We1b, We2b, waP, wbP);
  for (int g=0; g<31; g++){
    k_spec_ab<<<dim3(16,32),dim3(256),0,stream>>>(s3, waP, wbP, be1a, be1b, be2a, be2b, hb, g);
    k_spec_c <<<dim3(8,32,1),dim3(256),0,stream>>>(hb, We1c,be1c,We2c,be2c, rec, g);
  }
  k_final<<<dim3(2048),dim3(256),0,stream>>>(s3, rec, out);
}

// Round 7
// 1581.656 us; speedup vs baseline: 4.1814x; 1.7656x over previous
//
#include <hip/hip_runtime.h>
#include <hip/hip_bf16.h>
#include <stdint.h>

typedef unsigned short u16;
typedef unsigned int   u32;
typedef __attribute__((ext_vector_type(8))) short bf16x8;
typedef __attribute__((ext_vector_type(4))) float f32x4;

__device__ __forceinline__ float us2f(u16 u){ return __uint_as_float(((u32)u)<<16); }
__device__ __forceinline__ float lo2f(u32 w){ return __uint_as_float(w<<16); }
__device__ __forceinline__ float hi2f(u32 w){ return __uint_as_float(w & 0xffff0000u); }
__device__ __forceinline__ u16 f2us(float f){
  u32 u = __float_as_uint(f);
  u32 r = (u + 0x7FFFu + ((u>>16)&1u)) >> 16;   // RNE
  return (u16)r;
}
__device__ __forceinline__ u32 pk2(float a, float b){ return (u32)f2us(a) | ((u32)f2us(b)<<16); }

// ---------------- prep: x (b,r,w) f32 -> xT[b][w][r] bf16 ----------------
__global__ __launch_bounds__(256) void k_prep_x(const float* __restrict__ x, u16* __restrict__ xT){
  __shared__ float tile[64][65];
  const int b = blockIdx.x, t = threadIdx.x;
  #pragma unroll
  for (int q=0;q<4;q++){
    int idx = q*256 + t, r = idx>>4, w4 = (idx&15)*4;
    float4 v = *(const float4*)&x[((size_t)b*64 + r)*64 + w4];
    tile[r][w4]=v.x; tile[r][w4+1]=v.y; tile[r][w4+2]=v.z; tile[r][w4+3]=v.w;
  }
  __syncthreads();
  #pragma unroll
  for (int q=0;q<2;q++){
    int idx = q*256 + t, w = idx>>3, rc = idx&7;
    uint4 o;
    o.x = pk2(tile[rc*8+0][w], tile[rc*8+1][w]);
    o.y = pk2(tile[rc*8+2][w], tile[rc*8+3][w]);
    o.z = pk2(tile[rc*8+4][w], tile[rc*8+5][w]);
    o.w = pk2(tile[rc*8+6][w], tile[rc*8+7][w]);
    *(uint4*)&xT[((size_t)b*64 + w)*64 + rc*8] = o;
  }
}

// ---------------- prep: W (64h,31o,CI,64r,3dw) f32 -> Wp[h][i][dw][o32][r64] bf16 ----------------
__global__ __launch_bounds__(256) void k_prep_w(const float* __restrict__ W,
        u16* __restrict__ Wp, int CI){
  __shared__ float rowW[5952];   // [o 31][j 192]
  const int h = blockIdx.x, i = blockIdx.y, t = threadIdx.x;
  for (int idx=t; idx<1488; idx+=256){
    int o = idx/48, j4 = (idx - o*48)*4;
    float4 v = *(const float4*)&W[ (((size_t)h*31 + o)*CI + i)*192 + j4 ];
    *(float4*)&rowW[o*192 + j4] = v;
  }
  __syncthreads();
  for (int idx=t; idx<768; idx+=256){
    int dw = idx>>8, rem = idx&255, o = rem>>3, rc = rem&7;
    uint4 ov = {0,0,0,0};
    if (o < 31){
      const float* s = &rowW[o*192 + dw];
      ov.x = pk2(s[(rc*8+0)*3], s[(rc*8+1)*3]);
      ov.y = pk2(s[(rc*8+2)*3], s[(rc*8+3)*3]);
      ov.z = pk2(s[(rc*8+4)*3], s[(rc*8+5)*3]);
      ov.w = pk2(s[(rc*8+6)*3], s[(rc*8+7)*3]);
    }
    *(uint4*)&Wp[ ((((size_t)h*CI + i)*3 + dw)*32 + o)*64 + rc*8 ] = ov;
  }
}

// ---------------- spatial layer via MFMA, prepped inputs ----------------
// inT_g: [b][i][w][r] bf16 ; Wp: [h][i][dw][o32][r64] bf16 ; bias (64,31) f32
// mode 0: outF[b][o][h][w] f32 std ; mode 1: outT[b][o][w][h] bf16 transposed
__global__ __launch_bounds__(256) void k_spatial2(const u16* __restrict__ inT_g,
        const u16* __restrict__ Wp, const float* __restrict__ bias,
        float* __restrict__ outF, u16* __restrict__ outT, int CI, int mode){
  __shared__ __align__(16) u16 inT[2][66*72];   // [wext][r pad72], rows 0/65 zero borders
  const int t    = threadIdx.x;
  const int wv   = t>>6;
  const int lane = t&63;
  const int l15  = lane&15;
  const int quad = lane>>4;
  const int b    = blockIdx.x;
  const int hg   = blockIdx.y;
  const int h    = hg*4 + wv;

  if (t < 72){
    inT[0][t] = 0; inT[0][65*72 + t] = 0;
    inT[1][t] = 0; inT[1][65*72 + t] = 0;
  }

  f32x4 acc[2][4];
  #pragma unroll
  for (int n=0;n<2;n++)
    #pragma unroll
    for (int ms=0;ms<4;ms++) acc[n][ms] = (f32x4){0.f,0.f,0.f,0.f};

  for (int i=0;i<CI;i++){
    u16* L = inT[i&1];
    // stage A: 512 uint4 pure copy (rows w=0..63 -> wext=1..64)
    const uint4* src = (const uint4*)(inT_g + (size_t)(b*CI + i)*4096);
    #pragma unroll
    for (int q=0;q<2;q++){
      int idx = q*256 + t, row = idx>>3, ch = idx&7;
      *(uint4*)&L[(row+1)*72 + ch*8] = src[idx];
    }
    // B fragments straight from global (L2-hot), issued before the barrier
    const u16* wbase = Wp + ((size_t)h*CI + i)*3*32*64;
    bf16x8 bfr[2][3][2];
    #pragma unroll
    for (int dw=0;dw<3;dw++)
      #pragma unroll
      for (int n=0;n<2;n++)
        #pragma unroll
        for (int kh=0;kh<2;kh++)
          bfr[kh][dw][n] = *(const bf16x8*)&wbase[(dw*32 + n*16 + l15)*64 + kh*32 + quad*8];
    __syncthreads();
    #pragma unroll
    for (int kh=0; kh<2; kh++){
      #pragma unroll
      for (int dw=0; dw<3; dw++){
        bf16x8 afr[4];
        #pragma unroll
        for (int ms=0;ms<4;ms++)
          afr[ms] = *(const bf16x8*)&L[(ms*16 + l15 + dw)*72 + kh*32 + quad*8];
        #pragma unroll
        for (int n=0;n<2;n++)
          #pragma unroll
          for (int ms=0;ms<4;ms++)
            acc[n][ms] = __builtin_amdgcn_mfma_f32_16x16x32_bf16(afr[ms], bfr[kh][dw][n], acc[n][ms], 0,0,0);
      }
    }
  }
  // epilogue: D col(n)=lane&15 -> o, row(m)=quad*4+reg -> w
  #pragma unroll
  for (int n=0;n<2;n++){
    int o = n*16 + l15;
    if (o < 31){
      float bv = bias[h*31 + o];
      if (mode == 0){
        #pragma unroll
        for (int ms=0;ms<4;ms++){
          size_t base = (((size_t)b*31 + o)*64 + h)*64 + ms*16 + quad*4;
          #pragma unroll
          for (int reg=0;reg<4;reg++)
            outF[base + reg] = fmaxf(acc[n][ms][reg] + bv, 0.f);
        }
      } else {
        #pragma unroll
        for (int ms=0;ms<4;ms++){
          int w0 = ms*16 + quad*4;
          #pragma unroll
          for (int reg=0;reg<4;reg++)
            outT[ (((size_t)b*31 + o)*64 + (w0+reg))*64 + h ] = f2us(fmaxf(acc[n][ms][reg] + bv, 0.f));
        }
      }
    }
  }
}

// ---------------- prep: spec weights -> GEMM-ready bf16 ----------------
__global__ __launch_bounds__(256) void k_prep(
    const float* __restrict__ We1a, const float* __restrict__ We2a,
    const float* __restrict__ We1b, const float* __restrict__ We2b,
    u16* __restrict__ waP, u16* __restrict__ wbP){
  int t = blockIdx.x*256 + threadIdx.x;
  if (t < 17856){
    int g = t/576, rem = t - g*576, dx = rem>>6, c = rem&63;
    int C; const float* wa;
    if (g==0)      { C=2; wa = We1a; }
    else if (g==30){ C=2; wa = We1a + 64*2*81; }
    else           { C=3; wa = We2a + (size_t)(g-1)*64*3*81; }
    const float* wrow = wa + (size_t)c*C*81;
    u16* dst = waP + ((size_t)(g*9 + dx)*64 + c)*40;
    int Kr = C*9;
    for (int k=0;k<40;k++){
      u16 v = 0;
      if (k < Kr) v = f2us(wrow[k*9 + dx]);
      dst[k] = v;
    }
  } else if (t < 17856 + 992){
    int u = t - 17856; int g = u>>5, c2 = u&31;
    const float* wb;
    if (g==0)      wb = We1b;
    else if (g==30) wb = We1b + 32*64;
    else            wb = We2b + (size_t)(g-1)*32*64;
    u16* dst = wbP + ((size_t)g*32 + c2)*72;
    for (int k=0;k<64;k++) dst[k] = f2us(wb[c2*64 + k]);
    for (int k=64;k<72;k++) dst[k] = 0;
  }
}

// ---------------- spectral a+b via MFMA (gl-batched) ----------------
// hb out (bf16): [gl][b][c2][y][x]
__global__ __launch_bounds__(256) void k_spec_ab(
    const float* __restrict__ s3,
    const u16* __restrict__ waP, const u16* __restrict__ wbP,
    const float* __restrict__ be1a, const float* __restrict__ be1b,
    const float* __restrict__ be2a, const float* __restrict__ be2b,
    u16* __restrict__ hb, int g0){
  __shared__ __align__(16) unsigned char smem[69120];
  u16* Ba   = (u16*)smem;            // [9][64][40]  phase A
  u16* colT = (u16*)(smem + 46080);  // [4][72][40]  phase A
  u16* haT  = (u16*)smem;            // [256][72]    phase B (over Ba)
  u16* hbL  = (u16*)(smem + 46080);  // [32][288]    phase B (over colT)

  const int t = threadIdx.x;
  const int yo = blockIdx.x, b = blockIdx.y;
  const int gl = blockIdx.z;
  const int g  = g0 + gl;
  const int y0 = yo*4;
  const int wv = t>>6, lane = t&63, l15 = lane&15, quad = lane>>4;

  int C, cb; const float *ba, *bb;
  if (g==0)      { C=2; cb=0;  ba=be1a;           bb=be1b;        }
  else if (g==30){ C=2; cb=29; ba=be1a+64;        bb=be1b+32;     }
  else           { C=3; cb=g-1; ba=be2a+(size_t)(g-1)*64; bb=be2b+(size_t)(g-1)*32; }

  {
    uint4 z = {0,0,0,0};
    uint4* c4 = (uint4*)colT;
    #pragma unroll
    for (int j=0;j<6;j++){ int idx = j*256 + t; if (idx < 1440) c4[idx] = z; }
  }
  {
    const uint4* src = (const uint4*)(waP + (size_t)g*9*64*40);
    uint4* dst = (uint4*)Ba;
    #pragma unroll
    for (int j=0;j<12;j++){ int idx = j*256 + t; if (idx < 2880) dst[idx] = src[idx]; }
  }
  __syncthreads();

  for (int idx=t; idx<576; idx+=256){
    int i = idx/192, rem = idx-192*i, yext = rem>>4, x4 = rem&15;
    int yrow = y0 + yext - 4;
    if (i < C && yrow >= 0 && yrow < 64){
      float4 v = *(const float4*)&s3[ (((size_t)b*31 + cb + i)*64 + yrow)*64 + x4*4 ];
      u16 q0=f2us(v.x), q1=f2us(v.y), q2=f2us(v.z), q3=f2us(v.w);
      #pragma unroll
      for (int yl=0; yl<4; yl++){
        int dy = yext - yl;
        if (dy >= 0 && dy < 9){
          int k = i*9 + dy;
          int base = (yl*72 + x4*4 + 4)*40 + k;
          colT[base      ] = q0;
          colT[base + 40 ] = q1;
          colT[base + 80 ] = q2;
          colT[base + 120] = q3;
        }
      }
    }
  }
  __syncthreads();

  f32x4 acc[4][4];
  #pragma unroll
  for (int yl=0;yl<4;yl++)
    #pragma unroll
    for (int nf=0;nf<4;nf++) acc[yl][nf] = (f32x4){0.f,0.f,0.f,0.f};

  #pragma unroll
  for (int dx=0; dx<9; dx++){
    bf16x8 af[4];
    #pragma unroll
    for (int yl=0;yl<4;yl++)
      af[yl] = *(const bf16x8*)&colT[(yl*72 + wv*16 + l15 + dx)*40 + quad*8];
    #pragma unroll
    for (int nf=0;nf<4;nf++){
      bf16x8 bfr = *(const bf16x8*)&Ba[((dx*64) + nf*16 + l15)*40 + quad*8];
      #pragma unroll
      for (int yl=0;yl<4;yl++)
        acc[yl][nf] = __builtin_amdgcn_mfma_f32_16x16x32_bf16(af[yl], bfr, acc[yl][nf], 0,0,0);
    }
  }
  __syncthreads();

  #pragma unroll
  for (int nf=0;nf<4;nf++){
    float bav = ba[nf*16 + l15];
    #pragma unroll
    for (int yl=0;yl<4;yl++){
      int px = yl*64 + wv*16 + quad*4;
      #pragma unroll
      for (int reg=0;reg<4;reg++)
        haT[(px+reg)*72 + nf*16 + l15] = f2us(fmaxf(acc[yl][nf][reg] + bav, 0.f));
    }
  }
  __syncthreads();

  const u16* wb_g = wbP + (size_t)g*32*72;
  f32x4 acc2[4][2];
  #pragma unroll
  for (int j=0;j<4;j++){ acc2[j][0] = (f32x4){0.f,0.f,0.f,0.f}; acc2[j][1] = (f32x4){0.f,0.f,0.f,0.f}; }
  #pragma unroll
  for (int kh=0; kh<2; kh++){
    bf16x8 a2[4];
    #pragma unroll
    for (int j=0;j<4;j++)
      a2[j] = *(const bf16x8*)&haT[((wv*4+j)*16 + l15)*72 + kh*32 + quad*8];
    #pragma unroll
    for (int nf=0;nf<2;nf++){
      bf16x8 b2 = *(const bf16x8*)&wb_g[(nf*16 + l15)*72 + kh*32 + quad*8];
      #pragma unroll
      for (int j=0;j<4;j++)
        acc2[j][nf] = __builtin_amdgcn_mfma_f32_16x16x32_bf16(a2[j], b2, acc2[j][nf], 0,0,0);
    }
  }
  #pragma unroll
  for (int nf=0;nf<2;nf++){
    float bbv = bb[nf*16 + l15];
    #pragma unroll
    for (int j=0;j<4;j++){
      int px = (wv*4+j)*16 + quad*4;
      #pragma unroll
      for (int reg=0;reg<4;reg++)
        hbL[(nf*16+l15)*288 + px + reg] = f2us(fmaxf(acc2[j][nf][reg] + bbv, 0.f));
    }
  }
  __syncthreads();

  {
    int c2 = t>>3, xq = t&7;
    size_t base = (((size_t)gl*32 + b)*32 + c2)*4096 + (size_t)yo*256 + xq*32;
    #pragma unroll
    for (int q=0;q<4;q++)
      *(uint4*)&hb[base + q*8] = *(const uint4*)&hbL[c2*288 + xq*32 + q*8];
  }
}

// ---------------- spectral: 5x5 conv 32->1, writes rec f32 [g][b][y][x] ----------------
__global__ __launch_bounds__(256) void k_spec_c(
    const u16* __restrict__ hb, const float* __restrict__ We1c, const float* __restrict__ be1c,
    const float* __restrict__ We2c, const float* __restrict__ be2c,
    float* __restrict__ rec, int g0){
  __shared__ __align__(16) unsigned char smemC[52224 + 3200];
  u16*   hbT  = (u16*)smemC;                 // [32][12][68] bf16
  float* wcL  = (float*)(smemC + 52224);     // [32][25]
  float* redc = (float*)smemC;               // overlay after compute
  const int t  = threadIdx.x;
  const int y0 = blockIdx.x*8;
  const int b  = blockIdx.y;
  const int gl = blockIdx.z;
  const int g  = g0 + gl;
  const float *wc, *bc;
  if (g==0)      { wc = We1c;             bc = be1c;       }
  else if (g==30){ wc = We1c + 800;       bc = be1c + 1;   }
  else           { wc = We2c + (g-1)*800; bc = be2c + (g-1); }

  for (int idx=t; idx<26112; idx+=256){
    int c2 = idx/816, rem = idx-816*c2, row = rem/68, col = rem-68*row;
    int yg = y0-2+row, xg = col-2;
    u16 v = 0;
    if (yg>=0 && yg<64 && xg>=0 && xg<64)
      v = hb[ (((size_t)gl*32 + b)*32 + c2)*4096 + (size_t)yg*64 + xg ];
    hbT[idx] = v;
  }
  for (int idx=t; idx<800; idx+=256) wcL[idx] = wc[idx];
  __syncthreads();

  const int xt = t&7, yq = (t>>3)&7, cqt = t>>6;
  const int x0 = xt*8;
  float acc[8];
  #pragma unroll
  for (int p=0;p<8;p++) acc[p]=0.f;
  for (int c2 = cqt*8; c2 < cqt*8+8; c2++){
    #pragma unroll
    for (int dy=0;dy<5;dy++){
      const uint2* hp = (const uint2*)&hbT[(c2*12 + yq+dy)*68 + x0];
      uint2 v0 = hp[0], v1 = hp[1], v2 = hp[2];
      float h[12];
      h[0]=lo2f(v0.x); h[1]=hi2f(v0.x); h[2]=lo2f(v0.y); h[3]=hi2f(v0.y);
      h[4]=lo2f(v1.x); h[5]=hi2f(v1.x); h[6]=lo2f(v1.y); h[7]=hi2f(v1.y);
      h[8]=lo2f(v2.x); h[9]=hi2f(v2.x); h[10]=lo2f(v2.y); h[11]=hi2f(v2.y);
      #pragma unroll
      for (int dx=0;dx<5;dx++){
        float wv = wcL[c2*25 + dy*5 + dx];
        #pragma unroll
        for (int p=0;p<8;p++) acc[p] = fmaf(h[p+dx], wv, acc[p]);
      }
    }
  }
  __syncthreads();
  int slot = yq*8 + xt;
  if (cqt >= 2){
    #pragma unroll
    for (int p=0;p<8;p++) redc[((cqt-2)*64 + slot)*8 + p] = acc[p];
  }
  __syncthreads();
  if (cqt < 2){
    #pragma unroll
    for (int p=0;p<8;p++) acc[p] += redc[(cqt*64 + slot)*8 + p];
  }
  __syncthreads();
  if (cqt == 1){
    #pragma unroll
    for (int p=0;p<8;p++) redc[slot*8 + p] = acc[p];
  }
  __syncthreads();
  if (cqt == 0){
    float bcv = bc[0];
    size_t base = (((size_t)g*32 + b)*64 + (y0+yq))*64 + x0;
    #pragma unroll
    for (int p=0;p<8;p++) rec[base+p] = acc[p] + redc[slot*8 + p] + bcv;
  }
}

// ---------------- final: out[b,y,x,o] = s3[b,o,y,x] + rec[o,b,y,x] (f32) ----------------
__global__ __launch_bounds__(256) void k_final(const float* __restrict__ s3,
        const float* __restrict__ rec, float* __restrict__ out){
  __shared__ float tile[31][65];
  const int t = threadIdx.x;
  const int y = blockIdx.x & 63;
  const int b = blockIdx.x >> 6;
  for (int idx=t; idx<1984; idx+=256){
    int o = idx>>6, x = idx&63;
    tile[o][x] = s3[ (((size_t)b*31+o)*64 + y)*64 + x ]
               + rec[ (((size_t)o*32+b)*64 + y)*64 + x ];
  }
  __syncthreads();
  size_t base = ((size_t)b*4096 + (size_t)y*64)*31;
  for (int idx=t; idx<1984; idx+=256){
    int x = idx/31, o = idx-31*x;
    out[base+idx] = tile[o][x];
  }
}

extern "C" void kernel_launch(void* const* d_in, const int* in_sizes, int n_in,
                              void* d_out, int out_size, void* d_ws, size_t ws_size,
                              hipStream_t stream){
  const float* x    = (const float*)d_in[0];
  const float* W1   = (const float*)d_in[1];
  const float* b1   = (const float*)d_in[2];
  const float* W2   = (const float*)d_in[3];
  const float* b2   = (const float*)d_in[4];
  const float* W3   = (const float*)d_in[5];
  const float* b3   = (const float*)d_in[6];
  const float* We1a = (const float*)d_in[7];
  const float* be1a = (const float*)d_in[8];
  const float* We1b = (const float*)d_in[9];
  const float* be1b = (const float*)d_in[10];
  const float* We1c = (const float*)d_in[11];
  const float* be1c = (const float*)d_in[12];
  const float* We2a = (const float*)d_in[13];
  const float* be2a = (const float*)d_in[14];
  const float* We2b = (const float*)d_in[15];
  const float* be2b = (const float*)d_in[16];
  const float* We2c = (const float*)d_in[17];
  const float* be2c = (const float*)d_in[18];
  float* out = (float*)d_out;

  // ws layout (time-multiplexed):
  //  spatial phase: s3 @0 (15.5M) | Wp @16M (<=24.4M) | xT @42M (0.5M)
  //  spec phase:    s3 @0         | rec @16M (15.5M)  | hb 2 slabs @33030144 (16.8M)
  char* ws = (char*)d_ws;
  float* s3  = (float*)(ws);
  u16*   Wp  = (u16*)(ws + 16777216);
  u16*   xT  = (u16*)(ws + 44040192);
  float* rec = (float*)(ws + 16777216);
  u16*   hb  = (u16*)(ws + 33030144);

  // d_out scratch (dead until k_final):
  //  spatial phase: s1T @0 (8.13M), s2T @8126464 (8.13M)
  //  spec phase:    waP @0 (1.43M), wbP @1440000
  u16* s1T = (u16*)((char*)d_out);
  u16* s2T = (u16*)((char*)d_out + 8126464);
  u16* waP = (u16*)((char*)d_out);
  u16* wbP = (u16*)((char*)d_out + 1440000);

  dim3 gs(32,16), bs(256);
  k_prep_x<<<dim3(32),bs,0,stream>>>(x, xT);
  k_prep_w<<<dim3(64,1),bs,0,stream>>>(W1, Wp, 1);
  k_spatial2<<<gs,bs,0,stream>>>(xT,  Wp, b1, nullptr, s1T, 1, 1);
  k_prep_w<<<dim3(64,31),bs,0,stream>>>(W2, Wp, 31);
  k_spatial2<<<gs,bs,0,stream>>>(s1T, Wp, b2, nullptr, s2T, 31, 1);
  k_prep_w<<<dim3(64,31),bs,0,stream>>>(W3, Wp, 31);
  k_spatial2<<<gs,bs,0,stream>>>(s2T, Wp, b3, s3, nullptr, 31, 0);

  k_prep<<<dim3(74),bs,0,stream>>>(We1a, We2a, We1b, We2b, waP, wbP);
  for (int g0=0; g0<31; g0+=2){
    int c = 31 - g0; if (c > 2) c = 2;
    k_spec_ab<<<dim3(16,32,c),bs,0,stream>>>(s3, waP, wbP, be1a, be1b, be2a, be2b, hb, g0);
    k_spec_c <<<dim3(8,32,c),bs,0,stream>>>(hb, We1c,be1c,We2c,be2c, rec, g0);
  }
  k_final<<<dim3(2048),bs,0,stream>>>(s3, rec, out);
}